// Round 2
// baseline (230.367 us; speedup 1.0000x reference)
//
#include <hip/hip_runtime.h>

// Destroy operator: y = (U kron I2) @ x where U[i,i+1] = sqrt(i+1).
// Reduces to: out[r, :] = sqrt(r/2 + 1) * x[r+2, :] for r < 2D-2; last 2 rows = 0.
// x: (2D, B) fp32 row-major, D = 4096, B = 4096.
//
// Key structure: output rows 2b and 2b+1 share coefficient sqrt(b+1), and the
// read offset is exactly +2 rows. One block per row-PAIR: block b scales
// row-pair b+1 by sqrt(b+1) into row-pair b. Block-uniform coefficient,
// zero divergence (except the single zero-fill block b = D-1).
//
// 2 rows = 8192 floats = 2048 float4 per block; 256 threads x 8 float4 each.
// Batched 8-load-then-8-store for deep MLP (8 outstanding global_load_dwordx4
// per wave). 4096 blocks = 16 per CU, evenly divisible across 256 CUs.

constexpr int kD = 4096;
constexpr int kB = 4096;
constexpr int kVec4PerRow = kB / 4;          // 1024
constexpr int kVec4PerPair = 2 * kVec4PerRow; // 2048 float4 per row-pair
constexpr int kPerThread = 8;                 // 2048 / 256 threads

__global__ __launch_bounds__(256) void destroy_kernel(
    const float4* __restrict__ x, float4* __restrict__ y) {
    const int b = blockIdx.x;           // row-pair index, 0..D-1
    const int t = threadIdx.x;
    const int base = b * kVec4PerPair + t;

    if (b == kD - 1) {
        const float4 z = make_float4(0.f, 0.f, 0.f, 0.f);
#pragma unroll
        for (int j = 0; j < kPerThread; ++j)
            y[base + j * 256] = z;
        return;
    }

    const float c = sqrtf((float)(b + 1));   // block-uniform

    float4 v[kPerThread];
#pragma unroll
    for (int j = 0; j < kPerThread; ++j)
        v[j] = x[base + kVec4PerPair + j * 256];   // read row-pair b+1

#pragma unroll
    for (int j = 0; j < kPerThread; ++j)
        y[base + j * 256] = make_float4(c * v[j].x, c * v[j].y,
                                        c * v[j].z, c * v[j].w);
}

extern "C" void kernel_launch(void* const* d_in, const int* in_sizes, int n_in,
                              void* d_out, int out_size, void* d_ws, size_t ws_size,
                              hipStream_t stream) {
    const float4* x = (const float4*)d_in[0];
    float4* y = (float4*)d_out;
    destroy_kernel<<<dim3(kD), dim3(256), 0, stream>>>(x, y);
}

// Round 4
// 215.946 us; speedup vs baseline: 1.0668x; 1.0668x over previous
//
#include <hip/hip_runtime.h>

// Destroy operator: y = (U kron I2) @ x where U[i,i+1] = sqrt(i+1).
// Reduces to: out[r, :] = sqrt(r/2 + 1) * x[r+2, :] for r < 2D-2; last 2 rows = 0.
// x: (2D, B) fp32 row-major, D = 4096, B = 4096.
//
// One block per row-pair b: scales row-pair b+1 by sqrt(b+1) into row-pair b.
// Block-uniform coefficient, no divergence except the single zero block.
// 2048 float4 per block; 256 threads x 8 float4, batched 8-load-then-8-store
// (8 outstanding global_load_dwordx4 per wave — matters more with NT loads).
//
// R4: nontemporal load/store via native ext_vector_type (HIP_vector_type
// structs are rejected by __builtin_nontemporal_*). Zero-reuse streaming on
// both sides — nt skips cache allocation, avoiding L2/L3 pollution.

typedef float vf4 __attribute__((ext_vector_type(4)));

constexpr int kD = 4096;
constexpr int kB = 4096;
constexpr int kVec4PerRow = kB / 4;           // 1024
constexpr int kVec4PerPair = 2 * kVec4PerRow; // 2048 float4 per row-pair
constexpr int kPerThread = 8;                 // 2048 / 256 threads

__global__ __launch_bounds__(256) void destroy_kernel(
    const vf4* __restrict__ x, vf4* __restrict__ y) {
    const int b = blockIdx.x;           // row-pair index, 0..D-1
    const int t = threadIdx.x;
    const int base = b * kVec4PerPair + t;

    if (b == kD - 1) {
        const vf4 z = {0.f, 0.f, 0.f, 0.f};
#pragma unroll
        for (int j = 0; j < kPerThread; ++j)
            __builtin_nontemporal_store(z, &y[base + j * 256]);
        return;
    }

    const float c = sqrtf((float)(b + 1));   // block-uniform

    vf4 v[kPerThread];
#pragma unroll
    for (int j = 0; j < kPerThread; ++j)
        v[j] = __builtin_nontemporal_load(&x[base + kVec4PerPair + j * 256]);

#pragma unroll
    for (int j = 0; j < kPerThread; ++j)
        __builtin_nontemporal_store(c * v[j], &y[base + j * 256]);
}

extern "C" void kernel_launch(void* const* d_in, const int* in_sizes, int n_in,
                              void* d_out, int out_size, void* d_ws, size_t ws_size,
                              hipStream_t stream) {
    const vf4* x = (const vf4*)d_in[0];
    vf4* y = (vf4*)d_out;
    destroy_kernel<<<dim3(kD), dim3(256), 0, stream>>>(x, y);
}